// Round 6
// baseline (399.350 us; speedup 1.0000x reference)
//
#include <hip/hip_runtime.h>

// Fused causal attention head: B=4, T=4096, D=384, K=64.
// All operands FRAGMENT-LINEAR for 32x32x16 MFMA: frag = [lane(64)][j(8)] u16 (1KB),
// index: lane&31 = m/n, lane>>5 = k-half, j = k&7; ksegs of 16 k each.
// Yk/Yq: tile(b, t32) = 4 ksegs (feat 0..63)            -> 2048 u16
// Vt:    tile(b, d>>5, key>>7) = 8 ksegs (128 keys)     -> 4096 u16
// Wka/Wqa: tile(fout>>5) x 24 ksegs (fin)               -> 12288 u16 each x2
// Wvb:     tile(d>>5)    x 24 ksegs (fin)               -> 12288 u16 x12
// Softmax: fixed-base (no max) — scores/8 ~ O(1), exp2 args small, fp32-safe;
// partial (unnormalized) O and lsum are LINEAR -> cross-group merge is an add.

#define BB 4
#define TT 4096
#define DD 384

#define OWKA 0
#define OWQA 24576
#define OWVB 49152
#define OYK  196608
#define OYQ  1245184
#define OVT  2293760

#define C_EXP 0.18033688011112042f  // log2(e)/8

typedef __bf16 bf16x8 __attribute__((ext_vector_type(8)));
typedef float f32x16 __attribute__((ext_vector_type(16)));
typedef unsigned short u16x4 __attribute__((ext_vector_type(4)));

__device__ __forceinline__ unsigned short f2bf(float f) {
  unsigned int u = __builtin_bit_cast(unsigned int, f);
  u += 0x7FFFu + ((u >> 16) & 1u);
  return (unsigned short)(u >> 16);
}

__device__ __forceinline__ bf16x8 ldb8(const unsigned short* p) {
  return *reinterpret_cast<const bf16x8*>(p);
}

// ---------------- 1. Weight convert -> frag-linear (Wk/Wq A-frag, Wv B-frag) --------
__global__ __launch_bounds__(256) void convert_w(
    const float* __restrict__ Wk, const float* __restrict__ Wq,
    const float* __restrict__ Wv, unsigned short* __restrict__ ws) {
  int g = blockIdx.x * 256 + threadIdx.x;    // 512 rows x 96 float4 = 49152
  int row = g / 96;
  int fin = (g - row * 96) * 4;
  const float* src;
  unsigned short* dstbase;
  int m;
  if (row < 64)       { src = Wk + row * 384;         dstbase = ws + OWKA; m = row; }
  else if (row < 128) { src = Wq + (row - 64) * 384;  dstbase = ws + OWQA; m = row - 64; }
  else                { src = Wv + (row - 128) * 384; dstbase = ws + OWVB; m = row - 128; }
  float4 f = *reinterpret_cast<const float4*>(src + fin);
  u16x4 o;
  o[0] = f2bf(f.x); o[1] = f2bf(f.y); o[2] = f2bf(f.z); o[3] = f2bf(f.w);
  unsigned short* dst = dstbase + (m >> 5) * 12288 + (fin >> 4) * 512
                        + ((((fin >> 3) & 1) << 5) + (m & 31)) * 8 + (fin & 7);
  *reinterpret_cast<u16x4*>(dst) = o;
}

// ---------------- 2. Fused K/Q/V projection ----------------------------------------
__global__ __launch_bounds__(512) void proj_fused(
    const float* __restrict__ x, const unsigned short* __restrict__ ws_r,
    unsigned short* __restrict__ Yk, unsigned short* __restrict__ Yq,
    unsigned short* __restrict__ Vt) {
  __shared__ __align__(16) unsigned short xlds[24576];   // [t32(2)][kseg(24)][64][8]
  int tb = blockIdx.x;                        // 0..255
  int b = tb >> 6;
  int tid = threadIdx.x;
  {
    int r = tid >> 3, e = tid & 7;
    const float* xr = x + (tb * 64 + r) * DD + e * 48;
#pragma unroll
    for (int i = 0; i < 12; i++) {
      int fin = e * 48 + i * 4;
      float4 f = *reinterpret_cast<const float4*>(xr + i * 4);
      u16x4 o;
      o[0] = f2bf(f.x); o[1] = f2bf(f.y); o[2] = f2bf(f.z); o[3] = f2bf(f.w);
      unsigned short* dst = xlds + (r >> 5) * 12288 + (fin >> 4) * 512
                            + ((((fin >> 3) & 1) << 5) + (r & 31)) * 8 + (fin & 7);
      *reinterpret_cast<u16x4*>(dst) = o;
    }
  }
  __syncthreads();
  int wid = tid >> 6, lane = tid & 63;
  int l31 = lane & 31, h8 = lane >> 5;
  const f32x16 fz16 = {};
  if (wid < 2) {
    const unsigned short* Wa = ws_r + (wid ? OWQA : OWKA) + lane * 8;
    unsigned short* Ysel = (wid ? Yq : Yk);
    f32x16 acc[2][2];
    acc[0][0] = fz16; acc[0][1] = fz16; acc[1][0] = fz16; acc[1][1] = fz16;
    for (int ks = 0; ks < 24; ks++) {
      bf16x8 a0 = ldb8(Wa + ks * 512);
      bf16x8 a1 = ldb8(Wa + 12288 + ks * 512);
      bf16x8 b0 = ldb8(xlds + ks * 512 + lane * 8);
      bf16x8 b1 = ldb8(xlds + 12288 + ks * 512 + lane * 8);
      acc[0][0] = __builtin_amdgcn_mfma_f32_32x32x16_bf16(a0, b0, acc[0][0], 0, 0, 0);
      acc[0][1] = __builtin_amdgcn_mfma_f32_32x32x16_bf16(a0, b1, acc[0][1], 0, 0, 0);
      acc[1][0] = __builtin_amdgcn_mfma_f32_32x32x16_bf16(a1, b0, acc[1][0], 0, 0, 0);
      acc[1][1] = __builtin_amdgcn_mfma_f32_32x32x16_bf16(a1, b1, acc[1][1], 0, 0, 0);
    }
#pragma unroll
    for (int mt = 0; mt < 2; mt++)
#pragma unroll
      for (int nt = 0; nt < 2; nt++) {
        int tile = b * 128 + (tb & 63) * 2 + nt;
#pragma unroll
        for (int rg = 0; rg < 4; rg++) {
          u16x4 o;
#pragma unroll
          for (int i = 0; i < 4; i++) o[i] = f2bf(acc[mt][nt][rg * 4 + i]);
          *reinterpret_cast<u16x4*>(Ysel + tile * 2048 + (mt * 2 + (rg >> 1)) * 512
                                    + (((rg & 1) << 5) + l31) * 8 + 4 * h8) = o;
        }
      }
  } else {
    int vw = wid - 2;
    const unsigned short* Wb = ws_r + OWVB + vw * 2 * 12288 + lane * 8;
    f32x16 acc[2][2];
    acc[0][0] = fz16; acc[0][1] = fz16; acc[1][0] = fz16; acc[1][1] = fz16;
    for (int ks = 0; ks < 24; ks++) {
      bf16x8 a0 = ldb8(xlds + ks * 512 + lane * 8);
      bf16x8 a1 = ldb8(xlds + 12288 + ks * 512 + lane * 8);
      bf16x8 w0 = ldb8(Wb + ks * 512);
      bf16x8 w1 = ldb8(Wb + 12288 + ks * 512);
      acc[0][0] = __builtin_amdgcn_mfma_f32_32x32x16_bf16(a0, w0, acc[0][0], 0, 0, 0);
      acc[0][1] = __builtin_amdgcn_mfma_f32_32x32x16_bf16(a0, w1, acc[0][1], 0, 0, 0);
      acc[1][0] = __builtin_amdgcn_mfma_f32_32x32x16_bf16(a1, w0, acc[1][0], 0, 0, 0);
      acc[1][1] = __builtin_amdgcn_mfma_f32_32x32x16_bf16(a1, w1, acc[1][1], 0, 0, 0);
    }
    int k128 = (tb & 63) >> 1;               // key-block WITHIN batch
#pragma unroll
    for (int t32 = 0; t32 < 2; t32++)
#pragma unroll
      for (int dt = 0; dt < 2; dt++) {
        int dti = vw * 2 + dt;
        unsigned short* vbase = Vt + ((b * 12 + dti) * 32 + k128) * 4096;
#pragma unroll
        for (int rg = 0; rg < 4; rg++) {
          u16x4 o;
#pragma unroll
          for (int i = 0; i < 4; i++) o[i] = f2bf(acc[t32][dt][rg * 4 + i]);
          int kseg = 4 * (tb & 1) + t32 * 2 + (rg >> 1);
          *reinterpret_cast<u16x4*>(vbase + kseg * 512
                                    + (((rg & 1) << 5) + l31) * 8 + 4 * h8) = o;
        }
      }
  }
}

// ---------------- 3. Flash attention: dual key-parity groups, 512 thr --------------
// Block = (b, 32-q strip), 8 waves = (dq 0..3, kh 0..1). Group kh handles key-blocks
// kb==kh (mod 2) in lockstep (shared barrier); private dbuf P per group. Fixed-base
// softmax -> partial O/lsum add at the end. 512 blocks all co-resident: 16 waves/CU.
__global__ __launch_bounds__(512, 4) void flash_attn(
    const unsigned short* __restrict__ Yk, const unsigned short* __restrict__ Yq,
    const unsigned short* __restrict__ Vt, float* __restrict__ out) {
  __shared__ __align__(16) unsigned short pbuf[2][2][8192];  // [kh][dbuf][kseg(8)][64][8]
  __shared__ float lred[8][32];
  int blk = blockIdx.x;
  int b = blk & 3;
  int idx = blk >> 2;                          // 0..127
  int st = (blk < 256) ? (127 - idx) : (idx - 64);  // blk i & i+256 complementary
  int tid = threadIdx.x;
  int wid = tid >> 6, lane = tid & 63;
  int dq = wid & 3, kh = wid >> 2;
  int l31 = lane & 31, h8 = lane >> 5;
  const f32x16 fz16 = {};
  const unsigned short* qbase = Yq + (b * 128 + st) * 2048 + lane * 8;
  bf16x8 qf[4];
#pragma unroll
  for (int ks = 0; ks < 4; ks++) qf[ks] = ldb8(qbase + ks * 512);
  f32x16 acc[3];
  acc[0] = fz16; acc[1] = fz16; acc[2] = fz16;
  float psum = 0.f;
  int n128 = (st >> 2) + 1;
  int nI = (n128 + 1) >> 1;                    // lockstep iteration count
  int qrow = st * 32 + l31;
  const unsigned short* kbase = Yk + (b * 128 + dq) * 2048 + lane * 8;
  const unsigned short* vbase = Vt + ((b * 12 + dq * 3) * 32) * 4096 + lane * 8;
#pragma unroll 1
  for (int i = 0; i < nI; i++) {
    int kb = 2 * i + kh;
    bool active = kb < n128;
    unsigned short* pw = pbuf[kh][i & 1];
    bf16x8 vf0[8], vf1[8], vf2[8];
    if (active) {
      const unsigned short* kt = kbase + kb * 8192;
      bf16x8 kf[4];
#pragma unroll
      for (int ks = 0; ks < 4; ks++) kf[ks] = ldb8(kt + ks * 512);
      f32x16 sacc = fz16;
#pragma unroll
      for (int ks = 0; ks < 4; ks++)
        sacc = __builtin_amdgcn_mfma_f32_32x32x16_bf16(kf[ks], qf[ks], sacc, 0, 0, 0);
      // V loads issued here: latency hides under exp/pack + barrier
      const unsigned short* vt = vbase + kb * 4096;
#pragma unroll
      for (int g = 0; g < 8; g++) vf0[g] = ldb8(vt + g * 512);
#pragma unroll
      for (int g = 0; g < 8; g++) vf1[g] = ldb8(vt + 32 * 4096 + g * 512);
#pragma unroll
      for (int g = 0; g < 8; g++) vf2[g] = ldb8(vt + 64 * 4096 + g * 512);
      int kg0 = kb * 128 + dq * 32 + 4 * h8;
#pragma unroll
      for (int rg = 0; rg < 4; rg++) {
        u16x4 o;
#pragma unroll
        for (int j = 0; j < 4; j++) {
          int key = kg0 + rg * 8 + j;
          float pv = (key > qrow) ? 0.f : exp2f(sacc[rg * 4 + j] * C_EXP);
          psum += pv;
          o[j] = f2bf(pv);
        }
        int g = dq * 2 + (rg >> 1);
        *reinterpret_cast<u16x4*>(pw + g * 512 + ((rg & 1) * 32 + l31) * 8 + 4 * h8) = o;
      }
    }
    __syncthreads();
    if (active) {
#pragma unroll
      for (int g = 0; g < 8; g++) {
        bf16x8 pf = ldb8(pw + g * 512 + lane * 8);
        acc[0] = __builtin_amdgcn_mfma_f32_32x32x16_bf16(vf0[g], pf, acc[0], 0, 0, 0);
        acc[1] = __builtin_amdgcn_mfma_f32_32x32x16_bf16(vf1[g], pf, acc[1], 0, 0, 0);
        acc[2] = __builtin_amdgcn_mfma_f32_32x32x16_bf16(vf2[g], pf, acc[2], 0, 0, 0);
      }
    }
  }
  // merge lsum across all 8 waves
  psum += __shfl_xor(psum, 32);
  if (h8 == 0) lred[wid][l31] = psum;
  __syncthreads();
  float lt = lred[0][l31] + lred[1][l31] + lred[2][l31] + lred[3][l31]
           + lred[4][l31] + lred[5][l31] + lred[6][l31] + lred[7][l31];
  // merge partial O: kh=1 -> LDS -> kh=0 adds (3 rounds through pbuf[0][0], 16 KB)
  float* mbuf = (float*)&pbuf[0][0][0];
#pragma unroll 1
  for (int dt = 0; dt < 3; dt++) {
    float* mp = mbuf + dq * 1024 + lane * 16;
    if (kh == 1) {
#pragma unroll
      for (int rg = 0; rg < 4; rg++) {
        float4 o4;
        o4.x = acc[dt][rg * 4 + 0]; o4.y = acc[dt][rg * 4 + 1];
        o4.z = acc[dt][rg * 4 + 2]; o4.w = acc[dt][rg * 4 + 3];
        *reinterpret_cast<float4*>(mp + rg * 4) = o4;
      }
    }
    __syncthreads();
    if (kh == 0) {
#pragma unroll
      for (int rg = 0; rg < 4; rg++) {
        float4 o4 = *reinterpret_cast<const float4*>(mp + rg * 4);
        acc[dt][rg * 4 + 0] += o4.x; acc[dt][rg * 4 + 1] += o4.y;
        acc[dt][rg * 4 + 2] += o4.z; acc[dt][rg * 4 + 3] += o4.w;
      }
    }
    __syncthreads();
  }
  if (kh == 0) {
    float inv = 1.0f / lt;
    float* ob = out + (b * TT + st * 32 + l31) * DD + dq * 96;
#pragma unroll
    for (int dt = 0; dt < 3; dt++)
#pragma unroll
      for (int rg = 0; rg < 4; rg++) {
        float4 o4;
        o4.x = acc[dt][rg * 4 + 0] * inv; o4.y = acc[dt][rg * 4 + 1] * inv;
        o4.z = acc[dt][rg * 4 + 2] * inv; o4.w = acc[dt][rg * 4 + 3] * inv;
        *reinterpret_cast<float4*>(ob + dt * 32 + rg * 8 + h8 * 4) = o4;
      }
  }
}

extern "C" void kernel_launch(void* const* d_in, const int* in_sizes, int n_in,
                              void* d_out, int out_size, void* d_ws, size_t ws_size,
                              hipStream_t stream) {
  const float* x  = (const float*)d_in[0];
  const float* Wk = (const float*)d_in[1];
  const float* Wq = (const float*)d_in[2];
  const float* Wv = (const float*)d_in[3];
  unsigned short* ws = (unsigned short*)d_ws;
  unsigned short* Yk = ws + OYK;
  unsigned short* Yq = ws + OYQ;
  unsigned short* Vt = ws + OVT;

  convert_w<<<192, 256, 0, stream>>>(Wk, Wq, Wv, ws);
  proj_fused<<<256, 512, 0, stream>>>(x, ws, Yk, Yq, Vt);
  flash_attn<<<512, 512, 0, stream>>>(Yk, Yq, Vt, (float*)d_out);
}

// Round 7
// 297.610 us; speedup vs baseline: 1.3419x; 1.3419x over previous
//
#include <hip/hip_runtime.h>

// Fused causal attention head: B=4, T=4096, D=384, K=64.
// All operands FRAGMENT-LINEAR for 32x32x16 MFMA: frag = [lane(64)][j(8)] u16 (1KB),
// index: lane&31 = m/n, lane>>5 = k-half, j = k&7; ksegs of 16 k each.
// Yk/Yq: tile(b, t32) = 4 ksegs (feat 0..63)            -> 2048 u16
// Vt:    tile(b, d>>5, key>>7) = 8 ksegs (128 keys)     -> 4096 u16
// Softmax: fixed-base (no max) — scores/8 ~ O(1), fp32-safe; partial O/lsum linear.
// R5 lesson: NOTHING bulky may live across __syncthreads under a VGPR cap —
// V loads sit after the barrier so the compiler cannot be forced to spill.

#define BB 4
#define TT 4096
#define DD 384

#define OWKA 0
#define OWQA 24576
#define OWVB 49152
#define OYK  196608
#define OYQ  1245184
#define OVT  2293760

#define C_EXP 0.18033688011112042f  // log2(e)/8

typedef __bf16 bf16x8 __attribute__((ext_vector_type(8)));
typedef float f32x16 __attribute__((ext_vector_type(16)));
typedef unsigned short u16x4 __attribute__((ext_vector_type(4)));

__device__ __forceinline__ unsigned short f2bf(float f) {
  unsigned int u = __builtin_bit_cast(unsigned int, f);
  u += 0x7FFFu + ((u >> 16) & 1u);
  return (unsigned short)(u >> 16);
}

__device__ __forceinline__ bf16x8 ldb8(const unsigned short* p) {
  return *reinterpret_cast<const bf16x8*>(p);
}

// ---------------- 1. Weight convert -> frag-linear (Wk/Wq A-frag, Wv B-frag) --------
__global__ __launch_bounds__(256) void convert_w(
    const float* __restrict__ Wk, const float* __restrict__ Wq,
    const float* __restrict__ Wv, unsigned short* __restrict__ ws) {
  int g = blockIdx.x * 256 + threadIdx.x;    // 512 rows x 96 float4 = 49152
  int row = g / 96;
  int fin = (g - row * 96) * 4;
  const float* src;
  unsigned short* dstbase;
  int m;
  if (row < 64)       { src = Wk + row * 384;         dstbase = ws + OWKA; m = row; }
  else if (row < 128) { src = Wq + (row - 64) * 384;  dstbase = ws + OWQA; m = row - 64; }
  else                { src = Wv + (row - 128) * 384; dstbase = ws + OWVB; m = row - 128; }
  float4 f = *reinterpret_cast<const float4*>(src + fin);
  u16x4 o;
  o[0] = f2bf(f.x); o[1] = f2bf(f.y); o[2] = f2bf(f.z); o[3] = f2bf(f.w);
  unsigned short* dst = dstbase + (m >> 5) * 12288 + (fin >> 4) * 512
                        + ((((fin >> 3) & 1) << 5) + (m & 31)) * 8 + (fin & 7);
  *reinterpret_cast<u16x4*>(dst) = o;
}

// ---------------- 2. Fused K/Q/V projection ----------------------------------------
__global__ __launch_bounds__(512) void proj_fused(
    const float* __restrict__ x, const unsigned short* __restrict__ ws_r,
    unsigned short* __restrict__ Yk, unsigned short* __restrict__ Yq,
    unsigned short* __restrict__ Vt) {
  __shared__ __align__(16) unsigned short xlds[24576];   // [t32(2)][kseg(24)][64][8]
  int tb = blockIdx.x;                        // 0..255
  int b = tb >> 6;
  int tid = threadIdx.x;
  {
    int r = tid >> 3, e = tid & 7;
    const float* xr = x + (tb * 64 + r) * DD + e * 48;
#pragma unroll
    for (int i = 0; i < 12; i++) {
      int fin = e * 48 + i * 4;
      float4 f = *reinterpret_cast<const float4*>(xr + i * 4);
      u16x4 o;
      o[0] = f2bf(f.x); o[1] = f2bf(f.y); o[2] = f2bf(f.z); o[3] = f2bf(f.w);
      unsigned short* dst = xlds + (r >> 5) * 12288 + (fin >> 4) * 512
                            + ((((fin >> 3) & 1) << 5) + (r & 31)) * 8 + (fin & 7);
      *reinterpret_cast<u16x4*>(dst) = o;
    }
  }
  __syncthreads();
  int wid = tid >> 6, lane = tid & 63;
  int l31 = lane & 31, h8 = lane >> 5;
  const f32x16 fz16 = {};
  if (wid < 2) {
    const unsigned short* Wa = ws_r + (wid ? OWQA : OWKA) + lane * 8;
    unsigned short* Ysel = (wid ? Yq : Yk);
    f32x16 acc[2][2];
    acc[0][0] = fz16; acc[0][1] = fz16; acc[1][0] = fz16; acc[1][1] = fz16;
    for (int ks = 0; ks < 24; ks++) {
      bf16x8 a0 = ldb8(Wa + ks * 512);
      bf16x8 a1 = ldb8(Wa + 12288 + ks * 512);
      bf16x8 b0 = ldb8(xlds + ks * 512 + lane * 8);
      bf16x8 b1 = ldb8(xlds + 12288 + ks * 512 + lane * 8);
      acc[0][0] = __builtin_amdgcn_mfma_f32_32x32x16_bf16(a0, b0, acc[0][0], 0, 0, 0);
      acc[0][1] = __builtin_amdgcn_mfma_f32_32x32x16_bf16(a0, b1, acc[0][1], 0, 0, 0);
      acc[1][0] = __builtin_amdgcn_mfma_f32_32x32x16_bf16(a1, b0, acc[1][0], 0, 0, 0);
      acc[1][1] = __builtin_amdgcn_mfma_f32_32x32x16_bf16(a1, b1, acc[1][1], 0, 0, 0);
    }
#pragma unroll
    for (int mt = 0; mt < 2; mt++)
#pragma unroll
      for (int nt = 0; nt < 2; nt++) {
        int tile = b * 128 + (tb & 63) * 2 + nt;
#pragma unroll
        for (int rg = 0; rg < 4; rg++) {
          u16x4 o;
#pragma unroll
          for (int i = 0; i < 4; i++) o[i] = f2bf(acc[mt][nt][rg * 4 + i]);
          *reinterpret_cast<u16x4*>(Ysel + tile * 2048 + (mt * 2 + (rg >> 1)) * 512
                                    + (((rg & 1) << 5) + l31) * 8 + 4 * h8) = o;
        }
      }
  } else {
    int vw = wid - 2;
    const unsigned short* Wb = ws_r + OWVB + vw * 2 * 12288 + lane * 8;
    f32x16 acc[2][2];
    acc[0][0] = fz16; acc[0][1] = fz16; acc[1][0] = fz16; acc[1][1] = fz16;
    for (int ks = 0; ks < 24; ks++) {
      bf16x8 a0 = ldb8(xlds + ks * 512 + lane * 8);
      bf16x8 a1 = ldb8(xlds + 12288 + ks * 512 + lane * 8);
      bf16x8 w0 = ldb8(Wb + ks * 512);
      bf16x8 w1 = ldb8(Wb + 12288 + ks * 512);
      acc[0][0] = __builtin_amdgcn_mfma_f32_32x32x16_bf16(a0, w0, acc[0][0], 0, 0, 0);
      acc[0][1] = __builtin_amdgcn_mfma_f32_32x32x16_bf16(a0, w1, acc[0][1], 0, 0, 0);
      acc[1][0] = __builtin_amdgcn_mfma_f32_32x32x16_bf16(a1, w0, acc[1][0], 0, 0, 0);
      acc[1][1] = __builtin_amdgcn_mfma_f32_32x32x16_bf16(a1, w1, acc[1][1], 0, 0, 0);
    }
    int k128 = (tb & 63) >> 1;               // key-block WITHIN batch
#pragma unroll
    for (int t32 = 0; t32 < 2; t32++)
#pragma unroll
      for (int dt = 0; dt < 2; dt++) {
        int dti = vw * 2 + dt;
        unsigned short* vbase = Vt + ((b * 12 + dti) * 32 + k128) * 4096;
#pragma unroll
        for (int rg = 0; rg < 4; rg++) {
          u16x4 o;
#pragma unroll
          for (int i = 0; i < 4; i++) o[i] = f2bf(acc[t32][dt][rg * 4 + i]);
          int kseg = 4 * (tb & 1) + t32 * 2 + (rg >> 1);
          *reinterpret_cast<u16x4*>(vbase + kseg * 512
                                    + (((rg & 1) << 5) + l31) * 8 + 4 * h8) = o;
        }
      }
  }
}

// ---------------- 3. Flash attention: dual key-parity groups, 512 thr --------------
// Block = (b, 32-q strip), 8 waves = (dq 0..3, kh 0..1). Group kh handles key-blocks
// kb==kh (mod 2) in lockstep (shared barrier); private dbuf P per group. V loads are
// AFTER the barrier (cannot be hoisted across it) so nothing bulky lives across
// __syncthreads -> no spills under the 128-VGPR cap. 16 waves/CU.
__global__ __launch_bounds__(512, 4) void flash_attn(
    const unsigned short* __restrict__ Yk, const unsigned short* __restrict__ Yq,
    const unsigned short* __restrict__ Vt, float* __restrict__ out) {
  __shared__ __align__(16) unsigned short pbuf[2][2][8192];  // [kh][dbuf][kseg(8)][64][8]
  __shared__ float lred[8][32];
  int blk = blockIdx.x;
  int b = blk & 3;
  int idx = blk >> 2;                          // 0..127
  int st = (blk < 256) ? (127 - idx) : (idx - 64);  // blk i & i+256 complementary
  int tid = threadIdx.x;
  int wid = tid >> 6, lane = tid & 63;
  int dq = wid & 3, kh = wid >> 2;
  int l31 = lane & 31, h8 = lane >> 5;
  const f32x16 fz16 = {};
  const unsigned short* qbase = Yq + (b * 128 + st) * 2048 + lane * 8;
  bf16x8 qf[4];
#pragma unroll
  for (int ks = 0; ks < 4; ks++) qf[ks] = ldb8(qbase + ks * 512);
  f32x16 acc[3];
  acc[0] = fz16; acc[1] = fz16; acc[2] = fz16;
  float psum = 0.f;
  int n128 = (st >> 2) + 1;
  int nI = (n128 + 1) >> 1;                    // lockstep iteration count
  int qrow = st * 32 + l31;
  const unsigned short* kbase = Yk + (b * 128 + dq) * 2048 + lane * 8;
  const unsigned short* vbase = Vt + ((b * 12 + dq * 3) * 32) * 4096 + lane * 8;
#pragma unroll 1
  for (int i = 0; i < nI; i++) {
    int kb = 2 * i + kh;
    bool active = kb < n128;
    unsigned short* pw = pbuf[kh][i & 1];
    if (active) {
      const unsigned short* kt = kbase + kb * 8192;
      bf16x8 kf[4];
#pragma unroll
      for (int ks = 0; ks < 4; ks++) kf[ks] = ldb8(kt + ks * 512);
      f32x16 sacc = fz16;
#pragma unroll
      for (int ks = 0; ks < 4; ks++)
        sacc = __builtin_amdgcn_mfma_f32_32x32x16_bf16(kf[ks], qf[ks], sacc, 0, 0, 0);
      int kg0 = kb * 128 + dq * 32 + 4 * h8;
#pragma unroll
      for (int rg = 0; rg < 4; rg++) {
        u16x4 o;
#pragma unroll
        for (int j = 0; j < 4; j++) {
          int key = kg0 + rg * 8 + j;
          float pv = (key > qrow) ? 0.f : exp2f(sacc[rg * 4 + j] * C_EXP);
          psum += pv;
          o[j] = f2bf(pv);
        }
        int g = dq * 2 + (rg >> 1);
        *reinterpret_cast<u16x4*>(pw + g * 512 + ((rg & 1) * 32 + l31) * 8 + 4 * h8) = o;
      }
    }
    __syncthreads();
    if (active) {
      const unsigned short* vt = vbase + kb * 4096;
#pragma unroll
      for (int g = 0; g < 8; g++) {
        bf16x8 vf0 = ldb8(vt + g * 512);
        bf16x8 vf1 = ldb8(vt + 32 * 4096 + g * 512);
        bf16x8 vf2 = ldb8(vt + 64 * 4096 + g * 512);
        bf16x8 pf = ldb8(pw + g * 512 + lane * 8);
        acc[0] = __builtin_amdgcn_mfma_f32_32x32x16_bf16(vf0, pf, acc[0], 0, 0, 0);
        acc[1] = __builtin_amdgcn_mfma_f32_32x32x16_bf16(vf1, pf, acc[1], 0, 0, 0);
        acc[2] = __builtin_amdgcn_mfma_f32_32x32x16_bf16(vf2, pf, acc[2], 0, 0, 0);
      }
    }
  }
  // merge lsum across all 8 waves
  psum += __shfl_xor(psum, 32);
  if (h8 == 0) lred[wid][l31] = psum;
  __syncthreads();
  float lt = lred[0][l31] + lred[1][l31] + lred[2][l31] + lred[3][l31]
           + lred[4][l31] + lred[5][l31] + lred[6][l31] + lred[7][l31];
  // merge partial O: kh=1 -> LDS -> kh=0 adds (3 rounds through pbuf[0][0], 16 KB)
  float* mbuf = (float*)&pbuf[0][0][0];
#pragma unroll 1
  for (int dt = 0; dt < 3; dt++) {
    float* mp = mbuf + dq * 1024 + lane * 16;
    if (kh == 1) {
#pragma unroll
      for (int rg = 0; rg < 4; rg++) {
        float4 o4;
        o4.x = acc[dt][rg * 4 + 0]; o4.y = acc[dt][rg * 4 + 1];
        o4.z = acc[dt][rg * 4 + 2]; o4.w = acc[dt][rg * 4 + 3];
        *reinterpret_cast<float4*>(mp + rg * 4) = o4;
      }
    }
    __syncthreads();
    if (kh == 0) {
#pragma unroll
      for (int rg = 0; rg < 4; rg++) {
        float4 o4 = *reinterpret_cast<const float4*>(mp + rg * 4);
        acc[dt][rg * 4 + 0] += o4.x; acc[dt][rg * 4 + 1] += o4.y;
        acc[dt][rg * 4 + 2] += o4.z; acc[dt][rg * 4 + 3] += o4.w;
      }
    }
    __syncthreads();
  }
  if (kh == 0) {
    float inv = 1.0f / lt;
    float* ob = out + (b * TT + st * 32 + l31) * DD + dq * 96;
#pragma unroll
    for (int dt = 0; dt < 3; dt++)
#pragma unroll
      for (int rg = 0; rg < 4; rg++) {
        float4 o4;
        o4.x = acc[dt][rg * 4 + 0] * inv; o4.y = acc[dt][rg * 4 + 1] * inv;
        o4.z = acc[dt][rg * 4 + 2] * inv; o4.w = acc[dt][rg * 4 + 3] * inv;
        *reinterpret_cast<float4*>(ob + dt * 32 + rg * 8 + h8 * 4) = o4;
      }
  }
}

extern "C" void kernel_launch(void* const* d_in, const int* in_sizes, int n_in,
                              void* d_out, int out_size, void* d_ws, size_t ws_size,
                              hipStream_t stream) {
  const float* x  = (const float*)d_in[0];
  const float* Wk = (const float*)d_in[1];
  const float* Wq = (const float*)d_in[2];
  const float* Wv = (const float*)d_in[3];
  unsigned short* ws = (unsigned short*)d_ws;
  unsigned short* Yk = ws + OYK;
  unsigned short* Yq = ws + OYQ;
  unsigned short* Vt = ws + OVT;

  convert_w<<<192, 256, 0, stream>>>(Wk, Wq, Wv, ws);
  proj_fused<<<256, 512, 0, stream>>>(x, ws, Yk, Yq, Vt);
  flash_attn<<<512, 512, 0, stream>>>(Yk, Yq, Vt, (float*)d_out);
}

// Round 8
// 161.994 us; speedup vs baseline: 2.4652x; 1.8372x over previous
//
#include <hip/hip_runtime.h>

// Fused causal attention head: B=4, T=4096, D=384, K=64.
// All operands FRAGMENT-LINEAR for 32x32x16 MFMA: frag = [lane(64)][j(8)] u16 (1KB),
// index: lane&31 = m/n, lane>>5 = k-half, j = k&7; ksegs of 16 k each.
// Yk/Yq: tile(b, t32) = 4 ksegs (feat 0..63)            -> 2048 u16
// Vt:    tile(b, d>>5, key>>7) = 8 ksegs (128 keys)     -> 4096 u16
// Softmax: fixed-base (no max) — scores/8 ~ O(1), fp32-safe; partial O/lsum LINEAR,
// so long strips (st>=64) are split into front/back key-range blocks + add-merge.
// R5/R6 lesson: do NOT demand 4 waves/EU at 512 thr (128-reg cap -> scratch thrash).
// Flash stays at the proven (256,2) config; occupancy comes from grid 768.

#define TT 4096
#define DD 384

#define OWKA 0
#define OWQA 24576
#define OWVB 49152
#define OYK  196608
#define OYQ  1245184
#define OVT  2293760
#define OOB  8585216      // back partial O bf16: [b][s=st-64][32q][384d] = 3145728 u16
#define OLF  11730944     // front lsum fp32: [b][s][32] = 8192 f32 (16384 u16)
#define OLB  11747328     // back  lsum fp32: same size; ws end = 11763712 u16 = 23.5 MB

#define C_EXP 0.18033688011112042f  // log2(e)/8

typedef __bf16 bf16x8 __attribute__((ext_vector_type(8)));
typedef float f32x16 __attribute__((ext_vector_type(16)));
typedef unsigned short u16x4 __attribute__((ext_vector_type(4)));

__device__ __forceinline__ unsigned short f2bf(float f) {
  unsigned int u = __builtin_bit_cast(unsigned int, f);
  u += 0x7FFFu + ((u >> 16) & 1u);
  return (unsigned short)(u >> 16);
}

__device__ __forceinline__ float bf2f(unsigned short s) {
  unsigned int u = ((unsigned int)s) << 16;
  return __builtin_bit_cast(float, u);
}

__device__ __forceinline__ bf16x8 ldb8(const unsigned short* p) {
  return *reinterpret_cast<const bf16x8*>(p);
}

// ---------------- 1. Weight convert -> frag-linear (Wk/Wq A-frag, Wv B-frag) --------
__global__ __launch_bounds__(256) void convert_w(
    const float* __restrict__ Wk, const float* __restrict__ Wq,
    const float* __restrict__ Wv, unsigned short* __restrict__ ws) {
  int g = blockIdx.x * 256 + threadIdx.x;    // 512 rows x 96 float4 = 49152
  int row = g / 96;
  int fin = (g - row * 96) * 4;
  const float* src;
  unsigned short* dstbase;
  int m;
  if (row < 64)       { src = Wk + row * 384;         dstbase = ws + OWKA; m = row; }
  else if (row < 128) { src = Wq + (row - 64) * 384;  dstbase = ws + OWQA; m = row - 64; }
  else                { src = Wv + (row - 128) * 384; dstbase = ws + OWVB; m = row - 128; }
  float4 f = *reinterpret_cast<const float4*>(src + fin);
  u16x4 o;
  o[0] = f2bf(f.x); o[1] = f2bf(f.y); o[2] = f2bf(f.z); o[3] = f2bf(f.w);
  unsigned short* dst = dstbase + (m >> 5) * 12288 + (fin >> 4) * 512
                        + ((((fin >> 3) & 1) << 5) + (m & 31)) * 8 + (fin & 7);
  *reinterpret_cast<u16x4*>(dst) = o;
}

// ---------------- 2. Fused K/Q/V projection ----------------------------------------
__global__ __launch_bounds__(512) void proj_fused(
    const float* __restrict__ x, const unsigned short* __restrict__ ws_r,
    unsigned short* __restrict__ Yk, unsigned short* __restrict__ Yq,
    unsigned short* __restrict__ Vt) {
  __shared__ __align__(16) unsigned short xlds[24576];   // [t32(2)][kseg(24)][64][8]
  int tb = blockIdx.x;                        // 0..255
  int b = tb >> 6;
  int tid = threadIdx.x;
  // stage X, fully coalesced: flat float4 idx = tid + 512*i over the 64x384 tile
  {
    const float* xbase = x + tb * 64 * DD;
#pragma unroll
    for (int i = 0; i < 12; i++) {
      int idx = tid + 512 * i;                // float4 index in tile
      int r = idx / 96;
      int fin = (idx - r * 96) * 4;
      float4 f = *reinterpret_cast<const float4*>(xbase + idx * 4);
      u16x4 o;
      o[0] = f2bf(f.x); o[1] = f2bf(f.y); o[2] = f2bf(f.z); o[3] = f2bf(f.w);
      unsigned short* dst = xlds + (r >> 5) * 12288 + (fin >> 4) * 512
                            + ((((fin >> 3) & 1) << 5) + (r & 31)) * 8 + (fin & 7);
      *reinterpret_cast<u16x4*>(dst) = o;
    }
  }
  __syncthreads();
  int wid = tid >> 6, lane = tid & 63;
  int l31 = lane & 31, h8 = lane >> 5;
  const f32x16 fz16 = {};
  if (wid < 2) {
    const unsigned short* Wa = ws_r + (wid ? OWQA : OWKA) + lane * 8;
    unsigned short* Ysel = (wid ? Yq : Yk);
    f32x16 acc[2][2];
    acc[0][0] = fz16; acc[0][1] = fz16; acc[1][0] = fz16; acc[1][1] = fz16;
    for (int ks = 0; ks < 24; ks++) {
      bf16x8 a0 = ldb8(Wa + ks * 512);
      bf16x8 a1 = ldb8(Wa + 12288 + ks * 512);
      bf16x8 b0 = ldb8(xlds + ks * 512 + lane * 8);
      bf16x8 b1 = ldb8(xlds + 12288 + ks * 512 + lane * 8);
      acc[0][0] = __builtin_amdgcn_mfma_f32_32x32x16_bf16(a0, b0, acc[0][0], 0, 0, 0);
      acc[0][1] = __builtin_amdgcn_mfma_f32_32x32x16_bf16(a0, b1, acc[0][1], 0, 0, 0);
      acc[1][0] = __builtin_amdgcn_mfma_f32_32x32x16_bf16(a1, b0, acc[1][0], 0, 0, 0);
      acc[1][1] = __builtin_amdgcn_mfma_f32_32x32x16_bf16(a1, b1, acc[1][1], 0, 0, 0);
    }
#pragma unroll
    for (int mt = 0; mt < 2; mt++)
#pragma unroll
      for (int nt = 0; nt < 2; nt++) {
        int tile = b * 128 + (tb & 63) * 2 + nt;
#pragma unroll
        for (int rg = 0; rg < 4; rg++) {
          u16x4 o;
#pragma unroll
          for (int i = 0; i < 4; i++) o[i] = f2bf(acc[mt][nt][rg * 4 + i]);
          *reinterpret_cast<u16x4*>(Ysel + tile * 2048 + (mt * 2 + (rg >> 1)) * 512
                                    + (((rg & 1) << 5) + l31) * 8 + 4 * h8) = o;
        }
      }
  } else {
    int vw = wid - 2;
    const unsigned short* Wb = ws_r + OWVB + vw * 2 * 12288 + lane * 8;
    f32x16 acc[2][2];
    acc[0][0] = fz16; acc[0][1] = fz16; acc[1][0] = fz16; acc[1][1] = fz16;
    for (int ks = 0; ks < 24; ks++) {
      bf16x8 a0 = ldb8(xlds + ks * 512 + lane * 8);
      bf16x8 a1 = ldb8(xlds + 12288 + ks * 512 + lane * 8);
      bf16x8 w0 = ldb8(Wb + ks * 512);
      bf16x8 w1 = ldb8(Wb + 12288 + ks * 512);
      acc[0][0] = __builtin_amdgcn_mfma_f32_32x32x16_bf16(a0, w0, acc[0][0], 0, 0, 0);
      acc[0][1] = __builtin_amdgcn_mfma_f32_32x32x16_bf16(a0, w1, acc[0][1], 0, 0, 0);
      acc[1][0] = __builtin_amdgcn_mfma_f32_32x32x16_bf16(a1, w0, acc[1][0], 0, 0, 0);
      acc[1][1] = __builtin_amdgcn_mfma_f32_32x32x16_bf16(a1, w1, acc[1][1], 0, 0, 0);
    }
    int k128 = (tb & 63) >> 1;               // key-block WITHIN batch
#pragma unroll
    for (int t32 = 0; t32 < 2; t32++)
#pragma unroll
      for (int dt = 0; dt < 2; dt++) {
        int dti = vw * 2 + dt;
        unsigned short* vbase = Vt + ((b * 12 + dti) * 32 + k128) * 4096;
#pragma unroll
        for (int rg = 0; rg < 4; rg++) {
          u16x4 o;
#pragma unroll
          for (int i = 0; i < 4; i++) o[i] = f2bf(acc[t32][dt][rg * 4 + i]);
          int kseg = 4 * (tb & 1) + t32 * 2 + (rg >> 1);
          *reinterpret_cast<u16x4*>(vbase + kseg * 512
                                    + (((rg & 1) << 5) + l31) * 8 + 4 * h8) = o;
        }
      }
  }
}

// ---------------- 3. Flash attention: R4 structure + long-strip key-split -----------
// Blocks 0..511: (b, st in [64,127]) x {front, back} key halves, longest first.
// Blocks 512..767: (b, st in [0,63]) unsplit, longest first.
// mode 0: normalized -> out. mode 1 (front): raw fp32 -> out, lsum -> lf.
// mode 2 (back): bf16 partial -> ws, lsum -> lb.  merge_split combines.
__global__ __launch_bounds__(256, 2) void flash_attn(
    const unsigned short* __restrict__ Yk, const unsigned short* __restrict__ Yq,
    const unsigned short* __restrict__ Vt, float* __restrict__ out,
    unsigned short* __restrict__ obk, float* __restrict__ lf, float* __restrict__ lb) {
  __shared__ __align__(16) unsigned short pbuf[2][8192];  // [dbuf][kseg(8)][64][8]
  __shared__ float lred[4][32];
  int blk = blockIdx.x;
  int b, st, kb0, kb1, mode, n128;
  if (blk < 512) {
    b = blk & 3;
    int u = blk >> 2;                          // 0..127
    st = 127 - (u >> 1);
    n128 = (st >> 2) + 1;
    int front = (n128 + 1) >> 1;
    if ((u & 1) == 0) { kb0 = 0; kb1 = front; mode = 1; }
    else              { kb0 = front; kb1 = n128; mode = 2; }
  } else {
    int v = blk - 512;
    b = v & 3;
    st = 63 - (v >> 2);
    n128 = (st >> 2) + 1;
    kb0 = 0; kb1 = n128; mode = 0;
  }
  int wid = threadIdx.x >> 6, lane = threadIdx.x & 63;
  int l31 = lane & 31, h8 = lane >> 5;
  const f32x16 fz16 = {};
  const unsigned short* qbase = Yq + (b * 128 + st) * 2048 + lane * 8;
  bf16x8 qf[4];
#pragma unroll
  for (int ks = 0; ks < 4; ks++) qf[ks] = ldb8(qbase + ks * 512);
  f32x16 acc[3];
  acc[0] = fz16; acc[1] = fz16; acc[2] = fz16;
  float psum = 0.f;
  int qrow = st * 32 + l31;
  const unsigned short* kbase = Yk + (b * 128 + wid) * 2048 + lane * 8;
  const unsigned short* vbase = Vt + ((b * 12 + wid * 3) * 32) * 4096 + lane * 8;
#pragma unroll 1
  for (int kb = kb0; kb < kb1; kb++) {
    const unsigned short* kt = kbase + kb * 8192;
    bf16x8 kf[4];
#pragma unroll
    for (int ks = 0; ks < 4; ks++) kf[ks] = ldb8(kt + ks * 512);
    f32x16 sacc = fz16;
#pragma unroll
    for (int ks = 0; ks < 4; ks++)
      sacc = __builtin_amdgcn_mfma_f32_32x32x16_bf16(kf[ks], qf[ks], sacc, 0, 0, 0);
    int kg0 = kb * 128 + wid * 32 + 4 * h8;
    unsigned short* pw = pbuf[kb & 1];
#pragma unroll
    for (int rg = 0; rg < 4; rg++) {
      u16x4 o;
#pragma unroll
      for (int j = 0; j < 4; j++) {
        int key = kg0 + rg * 8 + j;
        float pv = (key > qrow) ? 0.f : exp2f(sacc[rg * 4 + j] * C_EXP);
        psum += pv;
        o[j] = f2bf(pv);
      }
      int g = wid * 2 + (rg >> 1);
      *reinterpret_cast<u16x4*>(pw + g * 512 + ((rg & 1) * 32 + l31) * 8 + 4 * h8) = o;
    }
    // V frags issued before the barrier (latency overlaps barrier wait); no cap -> no spill
    const unsigned short* vt = vbase + kb * 4096;
    bf16x8 vf0[8], vf1[8], vf2[8];
#pragma unroll
    for (int g = 0; g < 8; g++) vf0[g] = ldb8(vt + g * 512);
#pragma unroll
    for (int g = 0; g < 8; g++) vf1[g] = ldb8(vt + 32 * 4096 + g * 512);
#pragma unroll
    for (int g = 0; g < 8; g++) vf2[g] = ldb8(vt + 64 * 4096 + g * 512);
    __syncthreads();
    bf16x8 pf[8];
#pragma unroll
    for (int g = 0; g < 8; g++) pf[g] = ldb8(pw + g * 512 + lane * 8);
#pragma unroll
    for (int g = 0; g < 8; g++) {
      acc[0] = __builtin_amdgcn_mfma_f32_32x32x16_bf16(vf0[g], pf[g], acc[0], 0, 0, 0);
      acc[1] = __builtin_amdgcn_mfma_f32_32x32x16_bf16(vf1[g], pf[g], acc[1], 0, 0, 0);
      acc[2] = __builtin_amdgcn_mfma_f32_32x32x16_bf16(vf2[g], pf[g], acc[2], 0, 0, 0);
    }
  }
  psum += __shfl_xor(psum, 32);
  if (h8 == 0) lred[wid][l31] = psum;
  __syncthreads();
  float lt = lred[0][l31] + lred[1][l31] + lred[2][l31] + lred[3][l31];
  if (mode == 0) {
    float inv = 1.0f / lt;
    float* ob = out + (b * TT + st * 32 + l31) * DD + wid * 96;
#pragma unroll
    for (int dt = 0; dt < 3; dt++)
#pragma unroll
      for (int rg = 0; rg < 4; rg++) {
        float4 o4;
        o4.x = acc[dt][rg * 4 + 0] * inv; o4.y = acc[dt][rg * 4 + 1] * inv;
        o4.z = acc[dt][rg * 4 + 2] * inv; o4.w = acc[dt][rg * 4 + 3] * inv;
        *reinterpret_cast<float4*>(ob + dt * 32 + rg * 8 + h8 * 4) = o4;
      }
  } else if (mode == 1) {
    // front half: raw unnormalized fp32 to out, lsum to lf
    float* ob = out + (b * TT + st * 32 + l31) * DD + wid * 96;
#pragma unroll
    for (int dt = 0; dt < 3; dt++)
#pragma unroll
      for (int rg = 0; rg < 4; rg++) {
        float4 o4;
        o4.x = acc[dt][rg * 4 + 0]; o4.y = acc[dt][rg * 4 + 1];
        o4.z = acc[dt][rg * 4 + 2]; o4.w = acc[dt][rg * 4 + 3];
        *reinterpret_cast<float4*>(ob + dt * 32 + rg * 8 + h8 * 4) = o4;
      }
    if (wid == 0 && h8 == 0) lf[(b * 64 + st - 64) * 32 + l31] = lt;
  } else {
    // back half: bf16 partial to ws, lsum to lb
    unsigned short* ob = obk + ((b * 64 + st - 64) * 32 + l31) * DD + wid * 96;
#pragma unroll
    for (int dt = 0; dt < 3; dt++)
#pragma unroll
      for (int rg = 0; rg < 4; rg++) {
        u16x4 o;
#pragma unroll
        for (int i = 0; i < 4; i++) o[i] = f2bf(acc[dt][rg * 4 + i]);
        *reinterpret_cast<u16x4*>(ob + dt * 32 + rg * 8 + h8 * 4) = o;
      }
    if (wid == 0 && h8 == 0) lb[(b * 64 + st - 64) * 32 + l31] = lt;
  }
}

// ---------------- 4. Merge split strips: out = (front + back) / (lf + lb) -----------
__global__ __launch_bounds__(256) void merge_split(
    float* __restrict__ out, const unsigned short* __restrict__ obk,
    const float* __restrict__ lf, const float* __restrict__ lb) {
  int blk = blockIdx.x;                       // 256 = b(4) x s(64)
  int b = blk >> 6, s = blk & 63;
  int tid = threadIdx.x;
  int q = tid >> 3, g = tid & 7;              // 32 q x 8 segments of 48 d
  int base = (b * 64 + s) * 32 + q;
  float inv = 1.0f / (lf[base] + lb[base]);
  float* ro = out + (b * TT + (64 + s) * 32 + q) * DD + g * 48;
  const unsigned short* po = obk + base * DD + g * 48;
#pragma unroll
  for (int i = 0; i < 12; i++) {
    float4 o4 = *reinterpret_cast<const float4*>(ro + i * 4);
    u16x4 p = *reinterpret_cast<const u16x4*>(po + i * 4);
    o4.x = (o4.x + bf2f(p[0])) * inv;
    o4.y = (o4.y + bf2f(p[1])) * inv;
    o4.z = (o4.z + bf2f(p[2])) * inv;
    o4.w = (o4.w + bf2f(p[3])) * inv;
    *reinterpret_cast<float4*>(ro + i * 4) = o4;
  }
}

extern "C" void kernel_launch(void* const* d_in, const int* in_sizes, int n_in,
                              void* d_out, int out_size, void* d_ws, size_t ws_size,
                              hipStream_t stream) {
  const float* x  = (const float*)d_in[0];
  const float* Wk = (const float*)d_in[1];
  const float* Wq = (const float*)d_in[2];
  const float* Wv = (const float*)d_in[3];
  unsigned short* ws = (unsigned short*)d_ws;
  unsigned short* Yk  = ws + OYK;
  unsigned short* Yq  = ws + OYQ;
  unsigned short* Vt  = ws + OVT;
  unsigned short* obk = ws + OOB;
  float* lf = (float*)(ws + OLF);
  float* lb = (float*)(ws + OLB);

  convert_w<<<192, 256, 0, stream>>>(Wk, Wq, Wv, ws);
  proj_fused<<<256, 512, 0, stream>>>(x, ws, Yk, Yq, Vt);
  flash_attn<<<768, 256, 0, stream>>>(Yk, Yq, Vt, (float*)d_out, obk, lf, lb);
  merge_split<<<256, 256, 0, stream>>>((float*)d_out, obk, lf, lb);
}

// Round 9
// 159.618 us; speedup vs baseline: 2.5019x; 1.0149x over previous
//
#include <hip/hip_runtime.h>

// Fused causal attention head: B=4, T=4096, D=384, K=64.
// All operands FRAGMENT-LINEAR for 32x32x16 MFMA: frag = [lane(64)][j(8)] u16 (1KB).
// Yk/Yq: tile(b, t32) = 4 ksegs (feat 0..63)            -> 2048 u16
// Vt:    tile(b, d>>5, key>>7) = 8 ksegs (128 keys)     -> 4096 u16
// Flash R8: 64-q strips (halves K+V bytes per unit work vs 32-q), cooperative
// 128-key iterations, <=3-piece key-split (fixed-base softmax => partials add).
// R5/R6 lesson: no min-waves launch_bounds beyond (256,2); nothing bulky forced
// live across barriers under a reg cap.

#define TT 4096
#define DD 384

#define OWKA 0
#define OWQA 24576
#define OWVB 49152
#define OYK  196608
#define OYQ  1245184
#define OVT  2293760
#define OB1  8585216      // piece-1 partial bf16: [b][st-16 (48)][64q][384] = 4718592 u16
#define OB2  13303808     // piece-2 partial bf16: [b][st-48 (16)][64q][384] = 1572864 u16
#define OL0  14876672     // lsum fp32 [b][st][64q] = 16384 f32 (32768 u16)
#define OL1  14909440
#define OL2  14942208     // end 14974976 u16 = 29.95 MB

#define C_EXP 0.18033688011112042f  // log2(e)/8

typedef __bf16 bf16x8 __attribute__((ext_vector_type(8)));
typedef float f32x16 __attribute__((ext_vector_type(16)));
typedef unsigned short u16x4 __attribute__((ext_vector_type(4)));
typedef unsigned short u16x8 __attribute__((ext_vector_type(8)));

__device__ __forceinline__ unsigned short f2bf(float f) {
  unsigned int u = __builtin_bit_cast(unsigned int, f);
  u += 0x7FFFu + ((u >> 16) & 1u);
  return (unsigned short)(u >> 16);
}

__device__ __forceinline__ float bf2f(unsigned short s) {
  unsigned int u = ((unsigned int)s) << 16;
  return __builtin_bit_cast(float, u);
}

__device__ __forceinline__ bf16x8 ldb8(const unsigned short* p) {
  return *reinterpret_cast<const bf16x8*>(p);
}

// ---------------- 1. Weight convert -> frag-linear (Wk/Wq A-frag, Wv B-frag) --------
__global__ __launch_bounds__(256) void convert_w(
    const float* __restrict__ Wk, const float* __restrict__ Wq,
    const float* __restrict__ Wv, unsigned short* __restrict__ ws) {
  int g = blockIdx.x * 256 + threadIdx.x;    // 512 rows x 96 float4 = 49152
  int row = g / 96;
  int fin = (g - row * 96) * 4;
  const float* src;
  unsigned short* dstbase;
  int m;
  if (row < 64)       { src = Wk + row * 384;         dstbase = ws + OWKA; m = row; }
  else if (row < 128) { src = Wq + (row - 64) * 384;  dstbase = ws + OWQA; m = row - 64; }
  else                { src = Wv + (row - 128) * 384; dstbase = ws + OWVB; m = row - 128; }
  float4 f = *reinterpret_cast<const float4*>(src + fin);
  u16x4 o;
  o[0] = f2bf(f.x); o[1] = f2bf(f.y); o[2] = f2bf(f.z); o[3] = f2bf(f.w);
  unsigned short* dst = dstbase + (m >> 5) * 12288 + (fin >> 4) * 512
                        + ((((fin >> 3) & 1) << 5) + (m & 31)) * 8 + (fin & 7);
  *reinterpret_cast<u16x4*>(dst) = o;
}

// ---------------- 2. Fused K/Q/V projection ----------------------------------------
// X staged in LDS with kseg-rotate swizzle: logical slot (t32, ks, h, r31, j) stored
// at r31' = (r31+ks)&31 — b128 writes land on rotating bank groups (was 16-way).
__global__ __launch_bounds__(512) void proj_fused(
    const float* __restrict__ x, const unsigned short* __restrict__ ws_r,
    unsigned short* __restrict__ Yk, unsigned short* __restrict__ Yq,
    unsigned short* __restrict__ Vt) {
  __shared__ __align__(16) unsigned short xlds[24576];   // [t32(2)][kseg(24)][64][8]
  int tb = blockIdx.x;                        // 0..255
  int b = tb >> 6;
  int tid = threadIdx.x;
  // stage: 3072 jobs = 64 rows x 48 groups of 8 floats; thread does 6
  {
    const float* xbase = x + tb * 64 * DD;
#pragma unroll
    for (int i = 0; i < 6; i++) {
      int j = tid + 512 * i;
      int r = j / 48, g8 = j - r * 48;
      const float* src = xbase + r * DD + g8 * 8;
      float4 f0 = *reinterpret_cast<const float4*>(src);
      float4 f1 = *reinterpret_cast<const float4*>(src + 4);
      u16x8 o;
      o[0] = f2bf(f0.x); o[1] = f2bf(f0.y); o[2] = f2bf(f0.z); o[3] = f2bf(f0.w);
      o[4] = f2bf(f1.x); o[5] = f2bf(f1.y); o[6] = f2bf(f1.z); o[7] = f2bf(f1.w);
      int ks = g8 >> 1, hb = g8 & 1;
      int r31s = ((r & 31) + ks) & 31;        // swizzle
      unsigned short* dst = xlds + (r >> 5) * 12288 + ks * 512 + (hb * 32 + r31s) * 8;
      *reinterpret_cast<u16x8*>(dst) = o;
    }
  }
  __syncthreads();
  int wid = tid >> 6, lane = tid & 63;
  int l31 = lane & 31, h8 = lane >> 5;
  const f32x16 fz16 = {};
  if (wid < 2) {
    const unsigned short* Wa = ws_r + (wid ? OWQA : OWKA) + lane * 8;
    unsigned short* Ysel = (wid ? Yq : Yk);
    f32x16 acc[2][2];
    acc[0][0] = fz16; acc[0][1] = fz16; acc[1][0] = fz16; acc[1][1] = fz16;
    for (int ks = 0; ks < 24; ks++) {
      int sl = (lane & 32) | ((lane + ks) & 31);     // read through swizzle
      bf16x8 a0 = ldb8(Wa + ks * 512);
      bf16x8 a1 = ldb8(Wa + 12288 + ks * 512);
      bf16x8 b0 = ldb8(xlds + ks * 512 + sl * 8);
      bf16x8 b1 = ldb8(xlds + 12288 + ks * 512 + sl * 8);
      acc[0][0] = __builtin_amdgcn_mfma_f32_32x32x16_bf16(a0, b0, acc[0][0], 0, 0, 0);
      acc[0][1] = __builtin_amdgcn_mfma_f32_32x32x16_bf16(a0, b1, acc[0][1], 0, 0, 0);
      acc[1][0] = __builtin_amdgcn_mfma_f32_32x32x16_bf16(a1, b0, acc[1][0], 0, 0, 0);
      acc[1][1] = __builtin_amdgcn_mfma_f32_32x32x16_bf16(a1, b1, acc[1][1], 0, 0, 0);
    }
#pragma unroll
    for (int mt = 0; mt < 2; mt++)
#pragma unroll
      for (int nt = 0; nt < 2; nt++) {
        int tile = b * 128 + (tb & 63) * 2 + nt;
#pragma unroll
        for (int rg = 0; rg < 4; rg++) {
          u16x4 o;
#pragma unroll
          for (int i = 0; i < 4; i++) o[i] = f2bf(acc[mt][nt][rg * 4 + i]);
          *reinterpret_cast<u16x4*>(Ysel + tile * 2048 + (mt * 2 + (rg >> 1)) * 512
                                    + (((rg & 1) << 5) + l31) * 8 + 4 * h8) = o;
        }
      }
  } else {
    int vw = wid - 2;
    const unsigned short* Wb = ws_r + OWVB + vw * 2 * 12288 + lane * 8;
    f32x16 acc[2][2];
    acc[0][0] = fz16; acc[0][1] = fz16; acc[1][0] = fz16; acc[1][1] = fz16;
    for (int ks = 0; ks < 24; ks++) {
      int sl = (lane & 32) | ((lane + ks) & 31);
      bf16x8 a0 = ldb8(xlds + ks * 512 + sl * 8);
      bf16x8 a1 = ldb8(xlds + 12288 + ks * 512 + sl * 8);
      bf16x8 w0 = ldb8(Wb + ks * 512);
      bf16x8 w1 = ldb8(Wb + 12288 + ks * 512);
      acc[0][0] = __builtin_amdgcn_mfma_f32_32x32x16_bf16(a0, w0, acc[0][0], 0, 0, 0);
      acc[0][1] = __builtin_amdgcn_mfma_f32_32x32x16_bf16(a0, w1, acc[0][1], 0, 0, 0);
      acc[1][0] = __builtin_amdgcn_mfma_f32_32x32x16_bf16(a1, w0, acc[1][0], 0, 0, 0);
      acc[1][1] = __builtin_amdgcn_mfma_f32_32x32x16_bf16(a1, w1, acc[1][1], 0, 0, 0);
    }
    int k128 = (tb & 63) >> 1;               // key-block WITHIN batch
#pragma unroll
    for (int t32 = 0; t32 < 2; t32++)
#pragma unroll
      for (int dt = 0; dt < 2; dt++) {
        int dti = vw * 2 + dt;
        unsigned short* vbase = Vt + ((b * 12 + dti) * 32 + k128) * 4096;
#pragma unroll
        for (int rg = 0; rg < 4; rg++) {
          u16x4 o;
#pragma unroll
          for (int i = 0; i < 4; i++) o[i] = f2bf(acc[t32][dt][rg * 4 + i]);
          int kseg = 4 * (tb & 1) + t32 * 2 + (rg >> 1);
          *reinterpret_cast<u16x4*>(vbase + kseg * 512
                                    + (((rg & 1) << 5) + l31) * 8 + 4 * h8) = o;
        }
      }
  }
}

// ---------------- 3. Flash attention: 64-q strips, coop 128-key iters, 3-way split --
// Block = (b, 64-q strip st, piece). Wave wid: QK for keys [wid*32,+32) x both
// q-tiles; PV for d-range [wid*96,+96) x both q-tiles. P via dbuf LDS, 1 barrier/iter.
__global__ __launch_bounds__(256, 2) void flash_attn(
    const unsigned short* __restrict__ Yk, const unsigned short* __restrict__ Yq,
    const unsigned short* __restrict__ Vt, float* __restrict__ out,
    unsigned short* __restrict__ ob1, unsigned short* __restrict__ ob2,
    float* __restrict__ l0, float* __restrict__ l1, float* __restrict__ l2) {
  __shared__ __align__(16) unsigned short pbuf[2][2][8192];  // [dbuf][qt][kseg(8)][64][8]
  __shared__ float lred[4][2][32];
  int blk = blockIdx.x;
  int b = blk & 3;
  int u = blk >> 2;                            // 0..127, longest pieces first
  int st, piece, P;
  if (u < 32)       { st = 47 - (u >> 1); piece = u & 1; P = 2; }
  else if (u < 80)  { int v = u - 32; st = 63 - v / 3; piece = v % 3; P = 3; }
  else if (u < 88)  { st = 15 - (u - 80); piece = 0; P = 1; }
  else if (u < 120) { int v = u - 88; st = 31 - (v >> 1); piece = v & 1; P = 2; }
  else              { st = 7 - (u - 120); piece = 0; P = 1; }
  int n128 = (st >> 1) + 1;
  int kb0 = (n128 * piece) / P, kb1 = (n128 * (piece + 1)) / P;
  int wid = threadIdx.x >> 6, lane = threadIdx.x & 63;
  int l31 = lane & 31, h8 = lane >> 5;
  const f32x16 fz16 = {};
  bf16x8 qf[2][4];
#pragma unroll
  for (int qt = 0; qt < 2; qt++)
#pragma unroll
    for (int ks = 0; ks < 4; ks++)
      qf[qt][ks] = ldb8(Yq + (b * 128 + st * 2 + qt) * 2048 + ks * 512 + lane * 8);
  f32x16 acc[3][2];
#pragma unroll
  for (int dt = 0; dt < 3; dt++) { acc[dt][0] = fz16; acc[dt][1] = fz16; }
  float psum0 = 0.f, psum1 = 0.f;
  const unsigned short* kbase = Yk + (b * 128) * 2048 + lane * 8;
  const unsigned short* vbase = Vt + ((b * 12 + wid * 3) * 32) * 4096 + lane * 8;
#pragma unroll 1
  for (int kb = kb0; kb < kb1; kb++) {
    const unsigned short* kt = kbase + (kb * 4 + wid) * 2048;
    bf16x8 kf[4];
#pragma unroll
    for (int ks = 0; ks < 4; ks++) kf[ks] = ldb8(kt + ks * 512);
    f32x16 s0 = fz16, s1 = fz16;
#pragma unroll
    for (int ks = 0; ks < 4; ks++) {
      s0 = __builtin_amdgcn_mfma_f32_32x32x16_bf16(kf[ks], qf[0][ks], s0, 0, 0, 0);
      s1 = __builtin_amdgcn_mfma_f32_32x32x16_bf16(kf[ks], qf[1][ks], s1, 0, 0, 0);
    }
    int kg0 = kb * 128 + wid * 32 + 4 * h8;
    bool lastb = (kb == n128 - 1);             // only block that can cross diagonal
    unsigned short* pw = &pbuf[kb & 1][0][0];
#pragma unroll
    for (int qt = 0; qt < 2; qt++) {
      int qrow = st * 64 + qt * 32 + l31;
#pragma unroll
      for (int rg = 0; rg < 4; rg++) {
        u16x4 o;
#pragma unroll
        for (int j = 0; j < 4; j++) {
          float sv = qt ? s1[rg * 4 + j] : s0[rg * 4 + j];
          int key = kg0 + rg * 8 + j;
          float pv = (lastb && key > qrow) ? 0.f : exp2f(sv * C_EXP);
          if (qt) psum1 += pv; else psum0 += pv;
          o[j] = f2bf(pv);
        }
        int g = wid * 2 + (rg >> 1);
        *reinterpret_cast<u16x4*>(pw + qt * 8192 + g * 512
                                  + ((rg & 1) * 32 + l31) * 8 + 4 * h8) = o;
      }
    }
    const unsigned short* vt = vbase + kb * 4096;
    bf16x8 vf0[8], vf1[8], vf2[8];
#pragma unroll
    for (int g = 0; g < 8; g++) vf0[g] = ldb8(vt + g * 512);
#pragma unroll
    for (int g = 0; g < 8; g++) vf1[g] = ldb8(vt + 32 * 4096 + g * 512);
#pragma unroll
    for (int g = 0; g < 8; g++) vf2[g] = ldb8(vt + 64 * 4096 + g * 512);
    __syncthreads();
#pragma unroll
    for (int g = 0; g < 8; g++) {
      bf16x8 pf0 = ldb8(pw + g * 512 + lane * 8);
      bf16x8 pf1 = ldb8(pw + 8192 + g * 512 + lane * 8);
      acc[0][0] = __builtin_amdgcn_mfma_f32_32x32x16_bf16(vf0[g], pf0, acc[0][0], 0, 0, 0);
      acc[0][1] = __builtin_amdgcn_mfma_f32_32x32x16_bf16(vf0[g], pf1, acc[0][1], 0, 0, 0);
      acc[1][0] = __builtin_amdgcn_mfma_f32_32x32x16_bf16(vf1[g], pf0, acc[1][0], 0, 0, 0);
      acc[1][1] = __builtin_amdgcn_mfma_f32_32x32x16_bf16(vf1[g], pf1, acc[1][1], 0, 0, 0);
      acc[2][0] = __builtin_amdgcn_mfma_f32_32x32x16_bf16(vf2[g], pf0, acc[2][0], 0, 0, 0);
      acc[2][1] = __builtin_amdgcn_mfma_f32_32x32x16_bf16(vf2[g], pf1, acc[2][1], 0, 0, 0);
    }
  }
  psum0 += __shfl_xor(psum0, 32);
  psum1 += __shfl_xor(psum1, 32);
  if (h8 == 0) { lred[wid][0][l31] = psum0; lred[wid][1][l31] = psum1; }
  __syncthreads();
  float lt0 = lred[0][0][l31] + lred[1][0][l31] + lred[2][0][l31] + lred[3][0][l31];
  float lt1 = lred[0][1][l31] + lred[1][1][l31] + lred[2][1][l31] + lred[3][1][l31];
  if (P == 1) {
    float inv0 = 1.0f / lt0, inv1 = 1.0f / lt1;
#pragma unroll
    for (int qt = 0; qt < 2; qt++) {
      float inv = qt ? inv1 : inv0;
      float* ob = out + (b * TT + st * 64 + qt * 32 + l31) * DD + wid * 96;
#pragma unroll
      for (int dt = 0; dt < 3; dt++)
#pragma unroll
        for (int rg = 0; rg < 4; rg++) {
          float4 o4;
          o4.x = acc[dt][qt][rg * 4 + 0] * inv; o4.y = acc[dt][qt][rg * 4 + 1] * inv;
          o4.z = acc[dt][qt][rg * 4 + 2] * inv; o4.w = acc[dt][qt][rg * 4 + 3] * inv;
          *reinterpret_cast<float4*>(ob + dt * 32 + rg * 8 + h8 * 4) = o4;
        }
    }
  } else if (piece == 0) {
    // raw fp32 -> out, lsum -> l0
#pragma unroll
    for (int qt = 0; qt < 2; qt++) {
      float* ob = out + (b * TT + st * 64 + qt * 32 + l31) * DD + wid * 96;
#pragma unroll
      for (int dt = 0; dt < 3; dt++)
#pragma unroll
        for (int rg = 0; rg < 4; rg++) {
          float4 o4;
          o4.x = acc[dt][qt][rg * 4 + 0]; o4.y = acc[dt][qt][rg * 4 + 1];
          o4.z = acc[dt][qt][rg * 4 + 2]; o4.w = acc[dt][qt][rg * 4 + 3];
          *reinterpret_cast<float4*>(ob + dt * 32 + rg * 8 + h8 * 4) = o4;
        }
    }
    if (wid == 0 && h8 == 0) {
      l0[(b * 64 + st) * 64 + l31] = lt0;
      l0[(b * 64 + st) * 64 + 32 + l31] = lt1;
    }
  } else {
    unsigned short* obp;
    float* lp;
    if (piece == 1) { obp = ob1 + ((b * 48 + st - 16) * 64) * DD; lp = l1; }
    else            { obp = ob2 + ((b * 16 + st - 48) * 64) * DD; lp = l2; }
#pragma unroll
    for (int qt = 0; qt < 2; qt++) {
      unsigned short* ob = obp + (qt * 32 + l31) * DD + wid * 96;
#pragma unroll
      for (int dt = 0; dt < 3; dt++)
#pragma unroll
        for (int rg = 0; rg < 4; rg++) {
          u16x4 o;
#pragma unroll
          for (int i = 0; i < 4; i++) o[i] = f2bf(acc[dt][qt][rg * 4 + i]);
          *reinterpret_cast<u16x4*>(ob + dt * 32 + rg * 8 + h8 * 4) = o;
        }
    }
    if (wid == 0 && h8 == 0) {
      lp[(b * 64 + st) * 64 + l31] = lt0;
      lp[(b * 64 + st) * 64 + 32 + l31] = lt1;
    }
  }
}

// ---------------- 4. Merge split strips (st>=16): out = sum(pieces)/sum(lsum) -------
__global__ __launch_bounds__(256) void merge_split(
    float* __restrict__ out, const unsigned short* __restrict__ ob1,
    const unsigned short* __restrict__ ob2, const float* __restrict__ l0,
    const float* __restrict__ l1, const float* __restrict__ l2) {
  int blk = blockIdx.x;                       // 192 = b(4) x s(48), st = 16+s
  int b = blk / 48, s = blk - b * 48;
  int st = 16 + s;
  bool has2 = (st >= 48);
  int tid = threadIdx.x;
  int q = tid >> 2, seg = tid & 3;            // 64 q x 4 segs of 96 floats
  int qi = (b * 64 + st) * 64 + q;
  float lt = l0[qi] + l1[qi] + (has2 ? l2[qi] : 0.f);
  float inv = 1.0f / lt;
  float* ro = out + (b * TT + st * 64 + q) * DD + seg * 96;
  const unsigned short* p1 = ob1 + ((b * 48 + s) * 64 + q) * DD + seg * 96;
  const unsigned short* p2 = ob2 + ((b * 16 + st - 48) * 64 + q) * DD + seg * 96;
#pragma unroll
  for (int i = 0; i < 24; i++) {
    float4 o4 = *reinterpret_cast<const float4*>(ro + i * 4);
    u16x4 a = *reinterpret_cast<const u16x4*>(p1 + i * 4);
    o4.x += bf2f(a[0]); o4.y += bf2f(a[1]); o4.z += bf2f(a[2]); o4.w += bf2f(a[3]);
    if (has2) {
      u16x4 c = *reinterpret_cast<const u16x4*>(p2 + i * 4);
      o4.x += bf2f(c[0]); o4.y += bf2f(c[1]); o4.z += bf2f(c[2]); o4.w += bf2f(c[3]);
    }
    o4.x *= inv; o4.y *= inv; o4.z *= inv; o4.w *= inv;
    *reinterpret_cast<float4*>(ro + i * 4) = o4;
  }
}

extern "C" void kernel_launch(void* const* d_in, const int* in_sizes, int n_in,
                              void* d_out, int out_size, void* d_ws, size_t ws_size,
                              hipStream_t stream) {
  const float* x  = (const float*)d_in[0];
  const float* Wk = (const float*)d_in[1];
  const float* Wq = (const float*)d_in[2];
  const float* Wv = (const float*)d_in[3];
  unsigned short* ws = (unsigned short*)d_ws;
  unsigned short* Yk  = ws + OYK;
  unsigned short* Yq  = ws + OYQ;
  unsigned short* Vt  = ws + OVT;
  unsigned short* ob1 = ws + OB1;
  unsigned short* ob2 = ws + OB2;
  float* l0 = (float*)(ws + OL0);
  float* l1 = (float*)(ws + OL1);
  float* l2 = (float*)(ws + OL2);

  convert_w<<<192, 256, 0, stream>>>(Wk, Wq, Wv, ws);
  proj_fused<<<256, 512, 0, stream>>>(x, ws, Yk, Yq, Vt);
  flash_attn<<<512, 256, 0, stream>>>(Yk, Yq, Vt, (float*)d_out, ob1, ob2, l0, l1, l2);
  merge_split<<<192, 256, 0, stream>>>((float*)d_out, ob1, ob2, l0, l1, l2);
}